// Round 7
// baseline (42.515 us; speedup 1.0000x reference)
//
#include <hip/hip_runtime.h>

// LSTM B=65536, T=9, I=57, H=2 (4H=8) — two-pass, LDS-staged pass 1.
//
// R2-R6 post-mortem: every variant gathered x with 8x32B-segment instrs
// (1 instr / 256 useful bytes, 8 line-touches each) -> TA/L1-issue bound at
// ~41us, 2x over the 21us HBM floor. Fix: stage 64-row chunks to LDS with
// perfect float4/ds_write_b128 streams; group-cooperative dot reads LDS.
// gx layout [b][t][8]: offset = row*8+j (row-major (b,t) == x row order) ->
// zero division, wave stores are 256B contiguous.

#define B_TOTAL 65536
#define T_STEPS 9
#define I_DIM   57
#define NROWS   (B_TOTAL * T_STEPS)   // 589824
#define CHUNK_ROWS 64
#define CHUNK_DW   (CHUNK_ROWS * I_DIM)   // 3648 dwords, 14592 B (16B-aligned)
#define CHUNK_F4   (CHUNK_DW / 4)         // 912
#define CHUNKS_PER_BLOCK 4
#define P1_BLOCKS  (NROWS / CHUNK_ROWS / CHUNKS_PER_BLOCK)   // 2304

__device__ __forceinline__ float fast_tanh(float v) {
    // tanh(v) = 1 - 2/(exp(2v)+1); exp(2v) = exp2(2*log2e*v). Err ~1e-6.
    float e = __builtin_amdgcn_exp2f(2.885390082f * v);
    return 1.0f - 2.0f * __builtin_amdgcn_rcpf(e + 1.0f);
}
__device__ __forceinline__ float fast_sig(float v) {
    return 0.5f * fast_tanh(0.5f * v) + 0.5f;
}

// ---------------- Pass 1: gx precompute (LDS-staged) ----------------

__global__ __launch_bounds__(256)
void lstm_gx(const float* __restrict__ x,
             const float* __restrict__ W_ih,
             const float* __restrict__ b_ih,
             const float* __restrict__ b_hh,
             float* __restrict__ gx) {
    __shared__ float lds[2][CHUNK_DW];   // 29184 B double buffer

    const int tid = threadIdx.x;
    const int j   = tid & 7;     // gate lane
    const int grp = tid >> 3;    // 0..31 (row group within block)

    // Rotated weight slices (validated R3: absmax 0.0 on gx math).
    float wrot[8][8];
#pragma unroll
    for (int d = 0; d < 8; ++d) {
        const int g = (j + d) & 7;
        const float* wr = W_ih + g * I_DIM;
#pragma unroll
        for (int k = 0; k < 7; ++k) wrot[d][k] = wr[j + 8 * k];
        wrot[d][7] = (j == 0) ? wr[56] : 0.0f;
    }
    float bsum = b_ih[j] + b_hh[j];
#pragma unroll
    for (int d = 0; d < 8; ++d)
#pragma unroll
        for (int k = 0; k < 8; ++k)
            asm volatile("" : "+v"(wrot[d][k]));

    const int c0 = blockIdx.x * CHUNKS_PER_BLOCK;

    float4 st0, st1, st2, st3;

    // Issue global loads for chunk c into st regs (perfect float4 stream).
#define STAGE_LOAD(C) do {                                                  \
        const float4* xc_ = (const float4*)(x + (size_t)(C) * CHUNK_DW);    \
        st0 = xc_[tid];                                                     \
        st1 = xc_[256 + tid];                                               \
        st2 = xc_[512 + tid];                                               \
        if (tid < CHUNK_F4 - 768) st3 = xc_[768 + tid];                     \
    } while (0)

    // Write staged regs to LDS buffer S (ds_write_b128, stride-1: conflict-free).
#define STAGE_WRITE(S) do {                                                 \
        float4* L_ = (float4*)lds[S];                                       \
        L_[tid] = st0;                                                      \
        L_[256 + tid] = st1;                                                \
        L_[512 + tid] = st2;                                                \
        if (tid < CHUNK_F4 - 768) L_[768 + tid] = st3;                      \
    } while (0)

    // Compute 2 rows (grp, grp+32) of chunk C from LDS buffer S.
#define COMPUTE(S, C) do {                                                  \
        _Pragma("unroll")                                                   \
        for (int iter = 0; iter < 2; ++iter) {                              \
            const int rl_ = iter * 32 + grp;                                \
            const float* row_ = lds[S] + rl_ * I_DIM;                       \
            float xv_[8];                                                   \
            _Pragma("unroll")                                               \
            for (int k = 0; k < 7; ++k) xv_[k] = row_[j + 8 * k];           \
            xv_[7] = row_[56];   /* broadcast: pairs with wrot[d][7] */     \
            float acc_[8];                                                  \
            _Pragma("unroll")                                               \
            for (int d = 0; d < 8; ++d) {                                   \
                float s_ = wrot[d][0] * xv_[0];                             \
                _Pragma("unroll")                                           \
                for (int k = 1; k < 8; ++k) s_ += wrot[d][k] * xv_[k];      \
                acc_[d] = s_;                                               \
            }                                                               \
            float tot_ = acc_[0];                                           \
            _Pragma("unroll")                                               \
            for (int d = 1; d < 8; ++d)                                     \
                tot_ += __shfl(acc_[d], (j - d) & 7, 8);                    \
            tot_ += bsum;                                                   \
            const size_t R_ = (size_t)(C) * CHUNK_ROWS + rl_;               \
            gx[R_ * 8 + j] = tot_;   /* wave store: 256B contiguous */      \
        }                                                                   \
    } while (0)

    STAGE_LOAD(c0);
    STAGE_WRITE(0);

#pragma unroll
    for (int cc = 0; cc < CHUNKS_PER_BLOCK; ++cc) {
        __syncthreads();                       // lds[cc&1] ready for all waves
        if (cc + 1 < CHUNKS_PER_BLOCK) STAGE_LOAD(c0 + cc + 1);   // issue early
        COMPUTE(cc & 1, c0 + cc);              // compute hides HBM latency
        if (cc + 1 < CHUNKS_PER_BLOCK) STAGE_WRITE((cc + 1) & 1); // write late
    }
#undef STAGE_LOAD
#undef STAGE_WRITE
#undef COMPUTE
}

// ---------------- Pass 2: recurrence ----------------

__global__ __launch_bounds__(256)
void lstm_rec(const float* __restrict__ gx,
              const float* __restrict__ W_hh,
              const float* __restrict__ fc_w,
              const float* __restrict__ fc_b,
              float* __restrict__ out) {
    const int b = blockIdx.x * 256 + threadIdx.x;

    float w0[8], w1[8];
#pragma unroll
    for (int g = 0; g < 8; ++g) { w0[g] = W_hh[g * 2]; w1[g] = W_hh[g * 2 + 1]; }

    float h0 = 0.f, h1 = 0.f, c0 = 0.f, c1 = 0.f;

    // gx[b][t][8]: thread's 72 floats contiguous, 16B-aligned (288B stride).
    const float* gb = gx + (size_t)b * (T_STEPS * 8);
    float4 ga  = *(const float4*)(gb);
    float4 gbv = *(const float4*)(gb + 4);

#pragma unroll
    for (int t = 0; t < T_STEPS; ++t) {
        float4 na, nb;
        if (t + 1 < T_STEPS) {
            const float* p = gb + (t + 1) * 8;
            na = *(const float4*)(p);
            nb = *(const float4*)(p + 4);
        }
        // gate rows [i0,i1,f0,f1,g0,g1,o0,o1]
        const float i0 = fast_sig (ga.x  + h0 * w0[0] + h1 * w1[0]);
        const float i1 = fast_sig (ga.y  + h0 * w0[1] + h1 * w1[1]);
        const float f0 = fast_sig (ga.z  + h0 * w0[2] + h1 * w1[2]);
        const float f1 = fast_sig (ga.w  + h0 * w0[3] + h1 * w1[3]);
        const float g0 = fast_tanh(gbv.x + h0 * w0[4] + h1 * w1[4]);
        const float g1 = fast_tanh(gbv.y + h0 * w0[5] + h1 * w1[5]);
        const float o0 = fast_sig (gbv.z + h0 * w0[6] + h1 * w1[6]);
        const float o1 = fast_sig (gbv.w + h0 * w0[7] + h1 * w1[7]);
        c0 = f0 * c0 + i0 * g0;
        c1 = f1 * c1 + i1 * g1;
        h0 = o0 * fast_tanh(c0);
        h1 = o1 * fast_tanh(c1);
        if (t + 1 < T_STEPS) { ga = na; gbv = nb; }
    }

    out[b] = h0 * fc_w[0] + h1 * fc_w[1] + fc_b[0];
}

extern "C" void kernel_launch(void* const* d_in, const int* in_sizes, int n_in,
                              void* d_out, int out_size, void* d_ws, size_t ws_size,
                              hipStream_t stream) {
    const float* x    = (const float*)d_in[0];
    const float* W_ih = (const float*)d_in[1];
    const float* W_hh = (const float*)d_in[2];
    const float* b_ih = (const float*)d_in[3];
    const float* b_hh = (const float*)d_in[4];
    const float* fc_w = (const float*)d_in[5];
    const float* fc_b = (const float*)d_in[6];
    float* out = (float*)d_out;
    float* gx  = (float*)d_ws;   // NROWS*8*4 = 18.9 MB << ws_size

    lstm_gx<<<dim3(P1_BLOCKS), dim3(256), 0, stream>>>(x, W_ih, b_ih, b_hh, gx);
    lstm_rec<<<dim3(B_TOTAL / 256), dim3(256), 0, stream>>>(gx, W_hh, fc_w, fc_b, out);
}

// Round 8
// 33.741 us; speedup vs baseline: 1.2600x; 1.2600x over previous
//
#include <hip/hip_runtime.h>

// LSTM B=65536, T=9, I=57, H=2 (4H=8) — single-kernel, block-local two-phase.
//
// R2-R7 post-mortem: six structural variants all land at 42+-1.5us; adding a
// second kernel + 38MB gx round-trip changed nothing -> per-kernel inner loops
// are not the cost. This round: ONE dispatch, gx never leaves the CU.
//   Phase A: stream 9 chunks x 64 rows of x through double-buffered LDS
//            (float4 loads, validated R7 staging), group-dot (validated R3)
//            writes gx into padded LDS [row][9].
//   Phase B: one wave, thread b = one batch, 9-step recurrence from LDS
//            (pad 9 -> float-offset stride 81, gcd(81,32)=1: conflict-free),
//            coalesced 64-float out store.
// LDS 49,920 B -> 3 blocks/CU. 1024 blocks.

#define B_TOTAL 65536
#define T_STEPS 9
#define I_DIM   57
#define BATCH_PER_BLOCK 64
#define ROWS_PER_BLOCK (BATCH_PER_BLOCK * T_STEPS)   // 576
#define CHUNK_ROWS 64
#define N_CHUNKS   (ROWS_PER_BLOCK / CHUNK_ROWS)     // 9
#define CHUNK_DW   (CHUNK_ROWS * I_DIM)              // 3648 dwords, 14592 B
#define CHUNK_F4   (CHUNK_DW / 4)                    // 912
#define GX_PAD     9                                  // 8 gates + 1 pad
#define NBLOCKS    (B_TOTAL / BATCH_PER_BLOCK)       // 1024

__device__ __forceinline__ float fast_tanh(float v) {
    // tanh(v) = 1 - 2/(exp(2v)+1); exp(2v) = exp2(2*log2e*v). Err ~1e-6.
    float e = __builtin_amdgcn_exp2f(2.885390082f * v);
    return 1.0f - 2.0f * __builtin_amdgcn_rcpf(e + 1.0f);
}
__device__ __forceinline__ float fast_sig(float v) {
    return 0.5f * fast_tanh(0.5f * v) + 0.5f;
}

__global__ __launch_bounds__(256)
void lstm_onepass(const float* __restrict__ x,
                  const float* __restrict__ W_ih,
                  const float* __restrict__ W_hh,
                  const float* __restrict__ b_ih,
                  const float* __restrict__ b_hh,
                  const float* __restrict__ fc_w,
                  const float* __restrict__ fc_b,
                  float* __restrict__ out) {
    __shared__ float xs[2][CHUNK_DW];                 // 29184 B staging dbuf
    __shared__ float gxp[ROWS_PER_BLOCK * GX_PAD];    // 20736 B gate pre-acts

    const int tid = threadIdx.x;
    const int j   = tid & 7;     // gate lane
    const int grp = tid >> 3;    // row group within block, 0..31

    // Rotated weight slices (validated R3: exact). acc_[d] -> gate (j+d)&7.
    float wrot[8][8];
#pragma unroll
    for (int d = 0; d < 8; ++d) {
        const int g = (j + d) & 7;
        const float* wr = W_ih + g * I_DIM;
#pragma unroll
        for (int k = 0; k < 7; ++k) wrot[d][k] = wr[j + 8 * k];
        wrot[d][7] = (j == 0) ? wr[56] : 0.0f;
    }
    float bsum = b_ih[j] + b_hh[j];
#pragma unroll
    for (int d = 0; d < 8; ++d)
#pragma unroll
        for (int k = 0; k < 8; ++k)
            asm volatile("" : "+v"(wrot[d][k]));

    // Block's x tile: 576 rows, contiguous, 16B-aligned (576*228 % 16 == 0).
    const float* xblk = x + (size_t)blockIdx.x * (ROWS_PER_BLOCK * I_DIM);

    float4 st0, st1, st2, st3;

#define STAGE_LOAD(C) do {                                                  \
        const float4* xc_ = (const float4*)(xblk + (size_t)(C) * CHUNK_DW); \
        st0 = xc_[tid];                                                     \
        st1 = xc_[256 + tid];                                               \
        st2 = xc_[512 + tid];                                               \
        if (tid < CHUNK_F4 - 768) st3 = xc_[768 + tid];                     \
    } while (0)

#define STAGE_WRITE(S) do {                                                 \
        float4* L_ = (float4*)xs[S];                                        \
        L_[tid] = st0;                                                      \
        L_[256 + tid] = st1;                                                \
        L_[512 + tid] = st2;                                                \
        if (tid < CHUNK_F4 - 768) L_[768 + tid] = st3;                      \
    } while (0)

    // Compute 2 rows (grp, grp+32) of chunk C from LDS buffer S into gxp.
#define COMPUTE(S, C) do {                                                  \
        _Pragma("unroll")                                                   \
        for (int iter = 0; iter < 2; ++iter) {                              \
            const int rl_ = iter * 32 + grp;                                \
            const float* row_ = xs[S] + rl_ * I_DIM;                        \
            float xv_[8];                                                   \
            _Pragma("unroll")                                               \
            for (int k = 0; k < 7; ++k) xv_[k] = row_[j + 8 * k];           \
            xv_[7] = row_[56];   /* broadcast; pairs with wrot[d][7] */     \
            float acc_[8];                                                  \
            _Pragma("unroll")                                               \
            for (int d = 0; d < 8; ++d) {                                   \
                float s_ = wrot[d][0] * xv_[0];                             \
                _Pragma("unroll")                                           \
                for (int k = 1; k < 8; ++k) s_ += wrot[d][k] * xv_[k];      \
                acc_[d] = s_;                                               \
            }                                                               \
            /* rotate-gather (independent shuffles), explicit tree add */   \
            float t1_ = __shfl(acc_[1], (j - 1) & 7, 8);                    \
            float t2_ = __shfl(acc_[2], (j - 2) & 7, 8);                    \
            float t3_ = __shfl(acc_[3], (j - 3) & 7, 8);                    \
            float t4_ = __shfl(acc_[4], (j - 4) & 7, 8);                    \
            float t5_ = __shfl(acc_[5], (j - 5) & 7, 8);                    \
            float t6_ = __shfl(acc_[6], (j - 6) & 7, 8);                    \
            float t7_ = __shfl(acc_[7], (j - 7) & 7, 8);                    \
            float tot_ = ((acc_[0] + t1_) + (t2_ + t3_))                    \
                       + ((t4_ + t5_) + (t6_ + t7_)) + bsum;                \
            gxp[((C) * CHUNK_ROWS + rl_) * GX_PAD + j] = tot_;              \
        }                                                                   \
    } while (0)

    STAGE_LOAD(0);
    STAGE_WRITE(0);

#pragma unroll
    for (int cc = 0; cc < N_CHUNKS; ++cc) {
        __syncthreads();                               // xs[cc&1] ready
        if (cc + 1 < N_CHUNKS) STAGE_LOAD(cc + 1);     // issue early
        COMPUTE(cc & 1, cc);                           // hides HBM latency
        if (cc + 1 < N_CHUNKS) STAGE_WRITE((cc + 1) & 1);
    }
#undef STAGE_LOAD
#undef STAGE_WRITE
#undef COMPUTE

    __syncthreads();   // gxp complete

    // ---------------- Phase B: recurrence, one wave, 1 thread/batch --------
    if (tid < BATCH_PER_BLOCK) {
        float w0[8], w1[8];
#pragma unroll
        for (int g = 0; g < 8; ++g) {
            w0[g] = W_hh[g * 2];
            w1[g] = W_hh[g * 2 + 1];
        }

        float h0 = 0.f, h1 = 0.f, c0 = 0.f, c1 = 0.f;
        const float* gb = gxp + tid * (T_STEPS * GX_PAD);  // stride 81 floats

#pragma unroll
        for (int t = 0; t < T_STEPS; ++t) {
            const float* p = gb + t * GX_PAD;
            // gate rows [i0,i1,f0,f1,g0,g1,o0,o1]
            const float i0 = fast_sig (p[0] + h0 * w0[0] + h1 * w1[0]);
            const float i1 = fast_sig (p[1] + h0 * w0[1] + h1 * w1[1]);
            const float f0 = fast_sig (p[2] + h0 * w0[2] + h1 * w1[2]);
            const float f1 = fast_sig (p[3] + h0 * w0[3] + h1 * w1[3]);
            const float g0 = fast_tanh(p[4] + h0 * w0[4] + h1 * w1[4]);
            const float g1 = fast_tanh(p[5] + h0 * w0[5] + h1 * w1[5]);
            const float o0 = fast_sig (p[6] + h0 * w0[6] + h1 * w1[6]);
            const float o1 = fast_sig (p[7] + h0 * w0[7] + h1 * w1[7]);
            c0 = f0 * c0 + i0 * g0;
            c1 = f1 * c1 + i1 * g1;
            h0 = o0 * fast_tanh(c0);
            h1 = o1 * fast_tanh(c1);
        }

        out[blockIdx.x * BATCH_PER_BLOCK + tid] =
            h0 * fc_w[0] + h1 * fc_w[1] + fc_b[0];
    }
}

extern "C" void kernel_launch(void* const* d_in, const int* in_sizes, int n_in,
                              void* d_out, int out_size, void* d_ws, size_t ws_size,
                              hipStream_t stream) {
    const float* x    = (const float*)d_in[0];
    const float* W_ih = (const float*)d_in[1];
    const float* W_hh = (const float*)d_in[2];
    const float* b_ih = (const float*)d_in[3];
    const float* b_hh = (const float*)d_in[4];
    const float* fc_w = (const float*)d_in[5];
    const float* fc_b = (const float*)d_in[6];
    float* out = (float*)d_out;

    lstm_onepass<<<dim3(NBLOCKS), dim3(256), 0, stream>>>(
        x, W_ih, W_hh, b_ih, b_hh, fc_w, fc_b, out);
}